// Round 1
// baseline (169.991 us; speedup 1.0000x reference)
//
#include <hip/hip_runtime.h>

// Problem: B=4, C=12, D=32, H=128, W=128. S = D*H*W = 524288 voxels per b.
// Four scalar losses from one softmax pass. Memory-bound: ~109 MB read once.

#define S4 131072           // S / 4 (float4 groups per (b,c) plane)
#define BLOCKS_PER_B 128
#define THREADS 256
#define NVOX 524288.0f
#define SMOOTH 1e-5f

// Wave-64 reduction (result in lane 0)
#define WRED(v) { v += __shfl_down(v,32); v += __shfl_down(v,16); \
                  v += __shfl_down(v,8);  v += __shfl_down(v,4);  \
                  v += __shfl_down(v,2);  v += __shfl_down(v,1); }

// Per-voxel processing. COMP is the float4/int4 component name (x,y,z,w).
// NBG structure: ids[0]=0 always; id1 = t<=4 ? 2t+1 : t+5; id2 = t<=3 ? 2t+2 : -1.
#define PROC(COMP) do {                                                        \
  float xv[12];                                                                \
  _Pragma("unroll")                                                            \
  for (int c = 0; c < 12; ++c) xv[c] = x[c].COMP;                              \
  const int tgt = tg.COMP;                                                     \
  float m = xv[0];                                                             \
  _Pragma("unroll")                                                            \
  for (int c = 1; c < 12; ++c) m = fmaxf(m, xv[c]);                            \
  float e[12]; float es = 0.f;                                                 \
  _Pragma("unroll")                                                            \
  for (int c = 0; c < 12; ++c) { e[c] = __expf(xv[c] - m); es += e[c]; }       \
  const float r = 1.0f / es;                                                   \
  float g0 = 0.f, g1 = 0.f, g2 = 0.f;                                          \
  _Pragma("unroll")                                                            \
  for (int c = 0; c < 12; ++c) {                                               \
    const float p = e[c] * r;                                                  \
    aZ[c] += p * p;                                                            \
    const bool isT = (tgt == c);                                               \
    aC[c] += isT ? 1.f : 0.f;                                                  \
    if (c > 0) {                                                               \
      aIE[c] += isT ? 0.f : p;                                                 \
      aCE[c] += isT ? 0.f : __logf(1.f + p);                                   \
    }                                                                          \
    if (c == 0) g0 = p;                                                        \
    if (c==1||c==3||c==5||c==7||c==9||c==10||c==11) g1 = (id1==c) ? p : g1;    \
    if (c==2||c==4||c==6||c==8)                     g2 = (id2==c) ? p : g2;    \
  }                                                                            \
  const float s2v = v2 ? g2 : 0.f;                                             \
  zm0 += g0*g0; zm1 += g1*g1; zm2 += s2v*s2v;                                  \
  const bool t0 = (tgt == 0);                                                  \
  const bool t1 = (tgt == id1);                                                \
  const bool t2 = v2 && (tgt == id2);                                          \
  im0 += t0 ? g0 : 0.f; im1 += t1 ? g1 : 0.f; im2 += t2 ? g2 : 0.f;            \
  float m3 = fmaxf(g0, g1);                                                    \
  if (v2) m3 = fmaxf(m3, g2);                                                  \
  float s3 = __expf(g0 - m3) + __expf(g1 - m3);                                \
  if (v2) s3 += __expf(g2 - m3);                                               \
  const float lse = m3 + __logf(s3);                                           \
  const float gt = t0 ? g0 : (t1 ? g1 : g2);                                   \
  ces += lse - gt;                                                             \
} while (0)

__global__ void zero_acc(float* __restrict__ acc) {
  acc[threadIdx.x] = 0.f;   // 256 floats = 4 b * 64 slots
}

// Slot layout per b (stride 64):
//  0: ce_sum  1..3: inter_m[j]  4..6: z_m[j]  7: pad
//  8..19: z_e[c]  20..31: inter_e[c]  32..43: exc_ce[c]  44..55: cnt[c]
__global__ __launch_bounds__(THREADS, 2)
void marg_main(const float4* __restrict__ inp, const int4* __restrict__ tgtp,
               const int* __restrict__ task_id, float* __restrict__ acc) {
  const int b   = blockIdx.x >> 7;
  const int blk = blockIdx.x & (BLOCKS_PER_B - 1);
  const int t   = task_id[b];
  const int id1 = (t <= 4) ? 2*t + 1 : t + 5;
  const int id2 = (t <= 3) ? 2*t + 2 : -1;
  const bool v2 = (id2 >= 0);

  const float4* inB = inp  + (size_t)b * 12 * S4;
  const int4*   tgB = tgtp + (size_t)b * S4;

  float aZ[12], aIE[12], aCE[12], aC[12];
  #pragma unroll
  for (int c = 0; c < 12; ++c) { aZ[c]=0.f; aIE[c]=0.f; aCE[c]=0.f; aC[c]=0.f; }
  float zm0=0.f, zm1=0.f, zm2=0.f, im0=0.f, im1=0.f, im2=0.f, ces=0.f;

  #pragma unroll 1
  for (int s = blk * THREADS + (int)threadIdx.x; s < S4; s += BLOCKS_PER_B * THREADS) {
    float4 x[12];
    #pragma unroll
    for (int c = 0; c < 12; ++c) x[c] = inB[c * S4 + s];
    const int4 tg = tgB[s];
    PROC(x); PROC(y); PROC(z); PROC(w);
  }

  // Reduce 53 values: wave shuffle -> LDS -> one atomic per slot per block.
  WRED(ces); WRED(im0); WRED(im1); WRED(im2); WRED(zm0); WRED(zm1); WRED(zm2);
  #pragma unroll
  for (int c = 0; c < 12; ++c) { WRED(aZ[c]); WRED(aIE[c]); WRED(aCE[c]); WRED(aC[c]); }

  __shared__ float red[4][64];
  const int lane = threadIdx.x & 63;
  const int wv   = threadIdx.x >> 6;
  if (lane == 0) {
    float* rw = red[wv];
    rw[0]=ces; rw[1]=im0; rw[2]=im1; rw[3]=im2; rw[4]=zm0; rw[5]=zm1; rw[6]=zm2; rw[7]=0.f;
    #pragma unroll
    for (int c = 0; c < 12; ++c) {
      rw[8+c]=aZ[c]; rw[20+c]=aIE[c]; rw[32+c]=aCE[c]; rw[44+c]=aC[c];
    }
  }
  __syncthreads();
  if (threadIdx.x < 56) {
    const float sv = red[0][threadIdx.x] + red[1][threadIdx.x]
                   + red[2][threadIdx.x] + red[3][threadIdx.x];
    atomicAdd(acc + b * 64 + threadIdx.x, sv);
  }
}

__global__ void finalize(const float* __restrict__ acc,
                         const int* __restrict__ task_id,
                         float* __restrict__ out) {
  if (threadIdx.x != 0) return;
  float lmd = 0.f, lmce = 0.f, led = 0.f, lece = 0.f;
  for (int b = 0; b < 4; ++b) {
    const float* a = acc + b * 64;
    const int t   = task_id[b];
    const int id1 = (t <= 4) ? 2*t + 1 : t + 5;
    const int id2 = (t <= 3) ? 2*t + 2 : -1;

    lmce += a[0] / NVOX;

    // marginal dice (3 structures)
    const float y0 = a[44 + 0];
    const float y1 = a[44 + id1];
    const float d0 = (2.f*a[1] + SMOOTH) / (a[4] + y0 + SMOOTH);
    const float d1 = (2.f*a[2] + SMOOTH) / (a[5] + y1 + SMOOTH);
    float d2 = 1.f;
    if (id2 >= 0) {
      const float y2 = a[44 + id2];
      d2 = (2.f*a[3] + SMOOTH) / (a[6] + y2 + SMOOTH);
    }
    lmd += (1.f - d0) + (1.f - d1) + (1.f - d2);

    // exclusion dice: c=0 has te=0 -> inter=0, y=0, but z_e[0] counts
    led += SMOOTH / (a[8] + SMOOTH);
    for (int c = 1; c < 12; ++c) {
      const float ye = NVOX - a[44 + c];
      led += (2.f*a[20 + c] + SMOOTH) / (a[8 + c] + ye + SMOOTH);
    }

    // exclusion CE
    float s = 0.f;
    for (int c = 1; c < 12; ++c) s += a[32 + c];
    lece += s / NVOX;
  }
  out[0] = lmd  * 0.25f;
  out[1] = lmce * 0.25f;
  out[2] = led  * 0.25f;
  out[3] = lece * 0.25f;
}

extern "C" void kernel_launch(void* const* d_in, const int* in_sizes, int n_in,
                              void* d_out, int out_size, void* d_ws, size_t ws_size,
                              hipStream_t stream) {
  const float* inputs  = (const float*)d_in[0];
  const int*   targets = (const int*)d_in[1];
  const int*   task_id = (const int*)d_in[2];
  float* out = (float*)d_out;
  float* acc = (float*)d_ws;

  zero_acc<<<1, 256, 0, stream>>>(acc);
  marg_main<<<dim3(4 * BLOCKS_PER_B), THREADS, 0, stream>>>(
      (const float4*)inputs, (const int4*)targets, task_id, acc);
  finalize<<<1, 64, 0, stream>>>(acc, task_id, out);
}

// Round 2
// 167.183 us; speedup vs baseline: 1.0168x; 1.0168x over previous
//
#include <hip/hip_runtime.h>

// B=4, C=12, D=32, H=128, W=128. S = D*H*W = 524288 voxels per b.
// One pass: softmax over C, accumulate 32 scalars per b, finalize 4 losses.
// R1 post-mortem: 59us main kernel was latency-bound (2 waves/SIMD, 18% occ).
// R2: grid 512->1024 blocks (16 waves/CU), accumulators 53->32 via algebra:
//   z_m[j] == z_e[ids[j]];  inter_m[j] == pTgt_j;  targets in {0,id1,id2}
//   so hist/target-sums are 3 slots; exc-CE is one scalar.

#define S4 131072           // S/4 float4 groups per (b,c) plane
#define BLOCKS_PER_B 256    // 2 float4-groups (8 voxels) per thread
#define THREADS 256
#define NVOX 524288.0f
#define SMOOTH 1e-5f

#define WRED(v) { v += __shfl_down(v,32); v += __shfl_down(v,16); \
                  v += __shfl_down(v,8);  v += __shfl_down(v,4);  \
                  v += __shfl_down(v,2);  v += __shfl_down(v,1); }

// Per-voxel processing; COMP in {x,y,z,w}.
// id1 = t<=4 ? 2t+1 : t+5  (odd set + {10,11});  id2 = t<=3 ? 2t+2 : -1 (even set)
#define PROC(COMP) do {                                                        \
  float xv[12];                                                                \
  _Pragma("unroll")                                                            \
  for (int c = 0; c < 12; ++c) xv[c] = x[c].COMP;                              \
  const int tgt = tg.COMP;                                                     \
  float m = xv[0];                                                             \
  _Pragma("unroll")                                                            \
  for (int c = 1; c < 12; ++c) m = fmaxf(m, xv[c]);                            \
  float e[12]; float es = 0.f;                                                 \
  _Pragma("unroll")                                                            \
  for (int c = 0; c < 12; ++c) { e[c] = __expf(xv[c] - m); es += e[c]; }       \
  const float r = __builtin_amdgcn_rcpf(es);                                   \
  float p[12];                                                                 \
  _Pragma("unroll")                                                            \
  for (int c = 0; c < 12; ++c) {                                               \
    p[c] = e[c] * r;                                                           \
    aZ[c] += p[c] * p[c];                                                      \
    aP[c] += p[c];                                                             \
  }                                                                            \
  float slog = 0.f;                                                            \
  _Pragma("unroll")                                                            \
  for (int c = 1; c < 12; ++c) slog += __logf(1.f + p[c]);                     \
  const float g0 = p[0];                                                       \
  float g1 = 0.f, g2 = 0.f;                                                    \
  _Pragma("unroll")                                                            \
  for (int c = 1; c < 12; ++c) {                                               \
    if (c==1||c==3||c==5||c==7||c==9||c==10||c==11) g1 = (id1==c) ? p[c] : g1; \
    else                                            g2 = (id2==c) ? p[c] : g2; \
  }                                                                            \
  const bool t0 = (tgt == 0);                                                  \
  const bool t1 = (tgt == id1);                                                \
  const bool t2 = v2 && (tgt == id2);                                          \
  c0 += t0 ? 1.f : 0.f;  c1 += t1 ? 1.f : 0.f;  c2 += t2 ? 1.f : 0.f;          \
  p0S += t0 ? g0 : 0.f;  p1S += t1 ? g1 : 0.f;  p2S += t2 ? g2 : 0.f;          \
  const float pt = t1 ? g1 : (t2 ? g2 : 0.f);                                  \
  cesE += slog - __logf(1.f + pt);                                             \
  float m3 = fmaxf(g0, g1);                                                    \
  if (v2) m3 = fmaxf(m3, g2);                                                  \
  float s3 = __expf(g0 - m3) + __expf(g1 - m3);                                \
  if (v2) s3 += __expf(g2 - m3);                                               \
  const float lse = m3 + __logf(s3);                                           \
  const float gt = t0 ? g0 : (t1 ? g1 : g2);                                   \
  ces += lse - gt;                                                             \
} while (0)

__global__ void zero_acc(float* __restrict__ acc) {
  acc[threadIdx.x] = 0.f;   // 4 b * 64 slots
}

// Slot layout per b (stride 64):
//  0: ces (marg-CE NLL sum)   1: cesE (exc-CE sum)
//  2,3,4: cnt0,cnt1,cnt2      5,6,7: pTgt0,pTgt1,pTgt2
//  8..19: z[c] = sum p_c^2    20..31: pSum[c] = sum p_c
__global__ __launch_bounds__(THREADS, 4)
void marg_main(const float4* __restrict__ inp, const int4* __restrict__ tgtp,
               const int* __restrict__ task_id, float* __restrict__ acc) {
  const int b   = blockIdx.x / BLOCKS_PER_B;
  const int blk = blockIdx.x % BLOCKS_PER_B;
  const int t   = task_id[b];
  const int id1 = (t <= 4) ? 2*t + 1 : t + 5;
  const int id2 = (t <= 3) ? 2*t + 2 : -1;
  const bool v2 = (id2 >= 0);

  const float4* inB = inp  + (size_t)b * 12 * S4;
  const int4*   tgB = tgtp + (size_t)b * S4;

  float aZ[12], aP[12];
  #pragma unroll
  for (int c = 0; c < 12; ++c) { aZ[c]=0.f; aP[c]=0.f; }
  float ces=0.f, cesE=0.f, c0=0.f, c1=0.f, c2=0.f, p0S=0.f, p1S=0.f, p2S=0.f;

  #pragma unroll 1
  for (int it = 0; it < 2; ++it) {
    const int s = (blk * 2 + it) * THREADS + (int)threadIdx.x;
    float4 x[12];
    #pragma unroll
    for (int c = 0; c < 12; ++c) x[c] = inB[c * S4 + s];
    const int4 tg = tgB[s];
    PROC(x); PROC(y); PROC(z); PROC(w);
  }

  WRED(ces); WRED(cesE); WRED(c0); WRED(c1); WRED(c2);
  WRED(p0S); WRED(p1S); WRED(p2S);
  #pragma unroll
  for (int c = 0; c < 12; ++c) { WRED(aZ[c]); WRED(aP[c]); }

  __shared__ float red[4][32];
  const int lane = threadIdx.x & 63;
  const int wv   = threadIdx.x >> 6;
  if (lane == 0) {
    float* rw = red[wv];
    rw[0]=ces; rw[1]=cesE; rw[2]=c0; rw[3]=c1; rw[4]=c2;
    rw[5]=p0S; rw[6]=p1S; rw[7]=p2S;
    #pragma unroll
    for (int c = 0; c < 12; ++c) { rw[8+c]=aZ[c]; rw[20+c]=aP[c]; }
  }
  __syncthreads();
  if (threadIdx.x < 32) {
    const float sv = red[0][threadIdx.x] + red[1][threadIdx.x]
                   + red[2][threadIdx.x] + red[3][threadIdx.x];
    atomicAdd(acc + b * 64 + threadIdx.x, sv);
  }
}

__global__ void finalize(const float* __restrict__ acc,
                         const int* __restrict__ task_id,
                         float* __restrict__ out) {
  if (threadIdx.x != 0) return;
  float lmd = 0.f, lmce = 0.f, led = 0.f, lece = 0.f;
  for (int b = 0; b < 4; ++b) {
    const float* a = acc + b * 64;
    const int t   = task_id[b];
    const int id1 = (t <= 4) ? 2*t + 1 : t + 5;
    const int id2 = (t <= 3) ? 2*t + 2 : -1;

    lmce += a[0] / NVOX;
    lece += a[1] / NVOX;

    // marginal dice: inter_j = pTgt_j, y_j = cnt_j, z_j = z[ids[j]]
    const float d0 = (2.f*a[5] + SMOOTH) / (a[8 + 0]   + a[2] + SMOOTH);
    const float d1 = (2.f*a[6] + SMOOTH) / (a[8 + id1] + a[3] + SMOOTH);
    float d2 = 1.f;
    if (id2 >= 0)
      d2 = (2.f*a[7] + SMOOTH) / (a[8 + id2] + a[4] + SMOOTH);
    lmd += (1.f - d0) + (1.f - d1) + (1.f - d2);

    // exclusion dice: c=0 -> te=0 -> SMOOTH/(z0+SMOOTH)
    led += SMOOTH / (a[8] + SMOOTH);
    for (int c = 1; c < 12; ++c) {
      const float ptc  = (c == id1) ? a[6] : ((c == id2) ? a[7] : 0.f);
      const float cntc = (c == id1) ? a[3] : ((c == id2) ? a[4] : 0.f);
      const float inter = a[20 + c] - ptc;
      const float ye    = NVOX - cntc;
      led += (2.f*inter + SMOOTH) / (a[8 + c] + ye + SMOOTH);
    }
  }
  out[0] = lmd  * 0.25f;
  out[1] = lmce * 0.25f;
  out[2] = led  * 0.25f;
  out[3] = lece * 0.25f;
}

extern "C" void kernel_launch(void* const* d_in, const int* in_sizes, int n_in,
                              void* d_out, int out_size, void* d_ws, size_t ws_size,
                              hipStream_t stream) {
  const float* inputs  = (const float*)d_in[0];
  const int*   targets = (const int*)d_in[1];
  const int*   task_id = (const int*)d_in[2];
  float* out = (float*)d_out;
  float* acc = (float*)d_ws;

  zero_acc<<<1, 256, 0, stream>>>(acc);
  marg_main<<<dim3(4 * BLOCKS_PER_B), THREADS, 0, stream>>>(
      (const float4*)inputs, (const int4*)targets, task_id, acc);
  finalize<<<1, 64, 0, stream>>>(acc, task_id, out);
}